// Round 1
// baseline (404.884 us; speedup 1.0000x reference)
//
#include <hip/hip_runtime.h>

// Persistent-RNN: 256 blocks (1/CU) x 512 threads (8 waves, 2/SIMD).
// Each block owns 16 batch rows for all 200 timesteps.
// W_hh/w_ih f16 fragments live in VGPRs (per-wave N-slices, 19 K-chunks of 16);
// h lives in LDS f16 [16][436-stride], xe(t+1) staged to LDS by waves 6/7.
// MFMA 16x16x16_f16: A[m=l&15][k=4g+j], B[k=4g+j][n=l&15], D[m=4g+j][n=l&15].

#define SEQ    200
#define BATCHN 4096
#define EMBD   100
#define HIDN   300

#define KCH  19      // K-chunks of 16 covering hidden (304)
#define KCE  7       // K-chunks of 16 covering emb (112)
#define XE0  304     // xe region column offset in s_lds
#define SROW 436     // s_lds row stride in f16 (8B-multiple, bank-spread)
#define ROWS 16

typedef _Float16 half4 __attribute__((ext_vector_type(4)));
typedef float    f32x4 __attribute__((ext_vector_type(4)));

static __device__ __forceinline__ half4 h4cvt(f32x4 v) {
  half4 h; h[0]=(_Float16)v[0]; h[1]=(_Float16)v[1];
  h[2]=(_Float16)v[2]; h[3]=(_Float16)v[3];
  return h;
}
static __device__ __forceinline__ half4 h4zero() {
  half4 h; h[0]=(_Float16)0.f; h[1]=(_Float16)0.f;
  h[2]=(_Float16)0.f; h[3]=(_Float16)0.f;
  return h;
}
static __device__ __forceinline__ float tanh_fast(float x) {
  // tanh(x) = 1 - 2/(exp(2x)+1); exp via v_exp_f32 (2^y), ~2-3 ulp total
  float e = __builtin_amdgcn_exp2f(x * 2.8853900817779268f);
  float r = __builtin_amdgcn_rcpf(e + 1.0f);
  return __builtin_fmaf(-2.0f, r, 1.0f);
}

#define MFMA16(A,B,C) __builtin_amdgcn_mfma_f32_16x16x16f16((A),(B),(C),0,0,0)

#define STEP_BODY(NT_) do {                                                   \
    _Pragma("unroll")                                                         \
    for (int c = 0; c < KCH; c++) {                                           \
      const half4 a = *(const half4*)(a_base + c * 16);                       \
      acc[0] = MFMA16(a, whh[c][0], acc[0]);                                  \
      acc[1] = MFMA16(a, whh[c][1], acc[1]);                                  \
      if (NT_ == 3) acc[2] = MFMA16(a, whh[c][2], acc[2]);                    \
    }                                                                         \
    _Pragma("unroll")                                                         \
    for (int c = 0; c < KCE; c++) {                                           \
      const half4 a = *(const half4*)(a_base + XE0 + c * 16);                 \
      acc[0] = MFMA16(a, wih[c][0], acc[0]);                                  \
      acc[1] = MFMA16(a, wih[c][1], acc[1]);                                  \
      if (NT_ == 3) acc[2] = MFMA16(a, wih[c][2], acc[2]);                    \
    }                                                                         \
  } while (0)

__global__ __launch_bounds__(512, 2)
void rnn_fused(const int* __restrict__ x, const float* __restrict__ emb,
               const float* __restrict__ w_ih, const float* __restrict__ w_hh,
               const float* __restrict__ b_ih, const float* __restrict__ b_hh,
               const float* __restrict__ fc1w, const float* __restrict__ fc1b,
               const float* __restrict__ fc2w, const float* __restrict__ fc2b,
               float* __restrict__ out)
{
  __shared__ __align__(16) _Float16 s_lds[ROWS][SROW]; // h (cols 0..303) + xe (304..415)
  __shared__ __align__(16) float    h1f[ROWS][257];    // fc1 output, fp32
  __shared__ int x_lds[SEQ][16];

  const int tid  = (int)threadIdx.x;
  const int lane = tid & 63;
  const int wv   = tid >> 6;
  const int r    = lane & 15;   // A-row / B-col lane index
  const int g    = lane >> 4;   // k-group 0..3
  const int base = (int)blockIdx.x * ROWS;

  // N-tile assignment: 19 tiles of 16 -> waves 0..2 get 3, waves 3..7 get 2
  const int t0    = (wv < 3) ? wv * 3 : 9 + (wv - 3) * 2;
  const int ntile = (wv < 3) ? 3 : 2;

  // ---- stage x indices for this block's 16 rows (all 200 steps)
  for (int i = tid; i < SEQ * 16; i += 512)
    x_lds[i >> 4][i & 15] = x[(i >> 4) * BATCHN + base + (i & 15)];
  // ---- zero h+xe staging (padding cols must stay zero forever)
  for (int i = tid; i < ROWS * SROW; i += 512)
    (&s_lds[0][0])[i] = (_Float16)0.f;

  // ---- resident weight fragments (f16) + bias
  half4 whh[KCH][3];
  half4 wih[KCE][3];
  float bias[3];
  #pragma unroll
  for (int tt = 0; tt < 3; tt++) {
    const int n = (t0 + tt) * 16 + r;
    const bool nv = (tt < ntile) && (n < HIDN);
    bias[tt] = nv ? (b_ih[n] + b_hh[n]) : 0.f;
    #pragma unroll
    for (int c = 0; c < KCH; c++) {
      const int k = c * 16 + 4 * g;
      whh[c][tt] = (nv && k < HIDN)
          ? h4cvt(*(const f32x4*)(w_hh + (long)n * HIDN + k)) : h4zero();
    }
    #pragma unroll
    for (int c = 0; c < KCE; c++) {
      const int k = c * 16 + 4 * g;
      wih[c][tt] = (nv && k < EMBD)
          ? h4cvt(*(const f32x4*)(w_ih + (long)n * EMBD + k)) : h4zero();
    }
  }

  // xe gather duty: wave6 -> chunks 0..3, wave7 -> chunks 4..6
  const int gc0 = (wv == 6) ? 0 : 4;
  const int gcn = (wv == 6) ? 4 : 3;

  __syncthreads();

  // ---- pre-stage xe(t=0)
  if (wv >= 6) {
    const int idx = x_lds[0][r];
    const float* erow = emb + (long)idx * EMBD;
    #pragma unroll
    for (int j = 0; j < 4; j++) {
      const int c = gc0 + j, k = c * 16 + 4 * g;
      if (j < gcn && k < EMBD)
        *(half4*)&s_lds[r][XE0 + c * 16 + 4 * g] = h4cvt(*(const f32x4*)(erow + k));
    }
  }
  __syncthreads();

  const _Float16* a_base = &s_lds[r][4 * g];

  // =========================== main scan ===========================
  #pragma unroll 1
  for (int t = 0; t < SEQ; t++) {
    // issue next-step emb gathers early (latency hides under MFMAs)
    f32x4 xg[4];
    if (wv >= 6) {
      const int tn = (t + 1 < SEQ) ? t + 1 : t;
      const int idx = x_lds[tn][r];
      const float* erow = emb + (long)idx * EMBD;
      #pragma unroll
      for (int j = 0; j < 4; j++) {
        const int c = gc0 + j, k = c * 16 + 4 * g;
        if (j < gcn && k < EMBD) xg[j] = *(const f32x4*)(erow + k);
      }
    }

    f32x4 acc[3];
    #pragma unroll
    for (int tt = 0; tt < 3; tt++) {
      f32x4 v = {bias[tt], bias[tt], bias[tt], bias[tt]};
      acc[tt] = v;
    }

    if (ntile == 3) { STEP_BODY(3); } else { STEP_BODY(2); }

    __syncthreads();  // all A-reads of h/xe complete before overwrite

    // stage xe(t+1)
    if (wv >= 6) {
      #pragma unroll
      for (int j = 0; j < 4; j++) {
        const int c = gc0 + j, k = c * 16 + 4 * g;
        if (j < gcn && k < EMBD)
          *(half4*)&s_lds[r][XE0 + c * 16 + 4 * g] = h4cvt(xg[j]);
      }
    }
    // h_t = tanh(pre-act); D lane layout: row m = 4g+j, col n = l&15
    #pragma unroll
    for (int tt = 0; tt < 3; tt++) {
      if (tt < ntile) {
        const int n = (t0 + tt) * 16 + r;
        if (n < HIDN) {
          #pragma unroll
          for (int j = 0; j < 4; j++)
            s_lds[4 * g + j][n] = (_Float16)tanh_fast(acc[tt][j]);
        }
      }
    }
    __syncthreads();
  }

  // =========================== fc1 (relu) ===========================
  {
    f32x4 acc1[2];
    const int f0 = wv * 2;   // 16 n-tiles over 8 waves
    #pragma unroll
    for (int ft = 0; ft < 2; ft++) {
      const float bb = fc1b[(f0 + ft) * 16 + r];
      f32x4 v = {bb, bb, bb, bb};
      acc1[ft] = v;
    }
    #pragma unroll
    for (int c = 0; c < KCH; c++) {
      const half4 a = *(const half4*)(a_base + c * 16);   // ht from LDS
      const int k = c * 16 + 4 * g;
      #pragma unroll
      for (int ft = 0; ft < 2; ft++) {
        const int n = (f0 + ft) * 16 + r;
        const half4 b = (k < HIDN)
            ? h4cvt(*(const f32x4*)(fc1w + (long)n * HIDN + k)) : h4zero();
        acc1[ft] = MFMA16(a, b, acc1[ft]);
      }
    }
    #pragma unroll
    for (int ft = 0; ft < 2; ft++) {
      const int n = (f0 + ft) * 16 + r;
      #pragma unroll
      for (int j = 0; j < 4; j++) {
        const float v = acc1[ft][j];
        h1f[4 * g + j][n] = v > 0.f ? v : 0.f;
      }
    }
  }
  __syncthreads();

  // =========================== fc2 (fp32 scalar) ===========================
  if (wv == 0 && lane < 48) {
    const int m = lane / 3;
    const int n = lane - 3 * m;
    float s = fc2b[n];
    for (int k = 0; k < 256; k++)
      s = __builtin_fmaf(h1f[m][k], fc2w[n * 256 + k], s);
    out[(base + m) * 3 + n] = s;
  }
}

extern "C" void kernel_launch(void* const* d_in, const int* in_sizes, int n_in,
                              void* d_out, int out_size, void* d_ws, size_t ws_size,
                              hipStream_t stream) {
  (void)in_sizes; (void)n_in; (void)d_ws; (void)ws_size; (void)out_size;
  const int*   x   = (const int*)d_in[0];
  const float* emb = (const float*)d_in[1];
  const float* wih = (const float*)d_in[2];
  const float* whh = (const float*)d_in[3];
  const float* bih = (const float*)d_in[4];
  const float* bhh = (const float*)d_in[5];
  const float* f1w = (const float*)d_in[6];
  const float* f1b = (const float*)d_in[7];
  const float* f2w = (const float*)d_in[8];
  const float* f2b = (const float*)d_in[9];
  rnn_fused<<<BATCHN / ROWS, 512, 0, stream>>>(
      x, emb, wih, whh, bih, bhh, f1w, f1b, f2w, f2b, (float*)d_out);
}

// Round 2
// 337.589 us; speedup vs baseline: 1.1993x; 1.1993x over previous
//
#include <hip/hip_runtime.h>

// Persistent-RNN: 256 blocks (1/CU) x 512 threads (8 waves).
// Each block owns 16 batch rows for all 200 timesteps.
// K=32 MFMA (mfma_f32_16x16x32_f16): A/B lane layout: 8 contiguous k per lane,
//   k = 8*(lane>>4) + j;  D: col = lane&15, row = 4*(lane>>4) + j  (m89-verified).
// h + xe double-buffered in LDS -> ONE barrier per step.
// Weights held as half8 fragments in VGPR/AGPR per wave (N-slices).

#define SEQ    200
#define BATCHN 4096
#define EMBD   100
#define HIDN   300

#define KCH   10     // K-chunks of 32 covering hidden (320)
#define KCE   4      // K-chunks of 32 covering emb (128)
#define XE0   320    // xe column offset within a buffer
#define BSPAN 448    // one buffer span (320 h + 128 xe)
#define SROW  904    // 2*BSPAN + 8 pad (f16 elems; 1808 B/row, 16B-aligned)
#define ROWS  16

typedef _Float16 half8 __attribute__((ext_vector_type(8)));
typedef float    f32x4 __attribute__((ext_vector_type(4)));

static __device__ __forceinline__ f32x4 f4z() { f32x4 z = {0.f, 0.f, 0.f, 0.f}; return z; }

static __device__ __forceinline__ half8 h8cvt(f32x4 a, f32x4 b) {
  half8 h;
  h[0]=(_Float16)a[0]; h[1]=(_Float16)a[1]; h[2]=(_Float16)a[2]; h[3]=(_Float16)a[3];
  h[4]=(_Float16)b[0]; h[5]=(_Float16)b[1]; h[6]=(_Float16)b[2]; h[7]=(_Float16)b[3];
  return h;
}

// Load 8 f16 of row[k0..k0+7], zero-padded past kmax (kmax % 4 == 0 for all uses).
static __device__ __forceinline__ half8 loadw(const float* row, int k0, int kmax, bool nv) {
  f32x4 a = (nv && (k0 + 3 < kmax)) ? *(const f32x4*)(row + k0)     : f4z();
  f32x4 b = (nv && (k0 + 7 < kmax)) ? *(const f32x4*)(row + k0 + 4) : f4z();
  return h8cvt(a, b);
}

static __device__ __forceinline__ float tanh_fast(float x) {
  float e = __builtin_amdgcn_exp2f(x * 2.8853900817779268f);  // exp(2x)
  float r = __builtin_amdgcn_rcpf(e + 1.0f);
  return __builtin_fmaf(-2.0f, r, 1.0f);
}

#define MFMA32(A,B,C) __builtin_amdgcn_mfma_f32_16x16x32_f16((A),(B),(C),0,0,0)

#define STEP_BODY(NT_) do {                                                   \
    _Pragma("unroll")                                                         \
    for (int c = 0; c < KCH; c++) {                                           \
      const half8 a = *(const half8*)(ab + c * 32);                           \
      acc[0] = MFMA32(a, whh[c][0], acc[0]);                                  \
      acc[1] = MFMA32(a, whh[c][1], acc[1]);                                  \
      if (NT_ == 3) acc[2] = MFMA32(a, whh[c][2], acc[2]);                    \
    }                                                                         \
    _Pragma("unroll")                                                         \
    for (int c = 0; c < KCE; c++) {                                           \
      const half8 a = *(const half8*)(ab + XE0 + c * 32);                     \
      acc[0] = MFMA32(a, wih[c][0], acc[0]);                                  \
      acc[1] = MFMA32(a, wih[c][1], acc[1]);                                  \
      if (NT_ == 3) acc[2] = MFMA32(a, wih[c][2], acc[2]);                    \
    }                                                                         \
  } while (0)

__global__ __launch_bounds__(512, 2)
void rnn_fused(const int* __restrict__ x, const float* __restrict__ emb,
               const float* __restrict__ w_ih, const float* __restrict__ w_hh,
               const float* __restrict__ b_ih, const float* __restrict__ b_hh,
               const float* __restrict__ fc1w, const float* __restrict__ fc1b,
               const float* __restrict__ fc2w, const float* __restrict__ fc2b,
               float* __restrict__ out)
{
  __shared__ __align__(16) _Float16 s_lds[ROWS][SROW]; // 2 x (h 320 | xe 128)
  __shared__ __align__(16) float    h1f[ROWS][257];    // fc1 output
  __shared__ int x_lds[SEQ][16];

  const int tid  = (int)threadIdx.x;
  const int lane = tid & 63;
  const int wv   = tid >> 6;
  const int r    = lane & 15;   // A-row / B-col / D-col lane index
  const int g    = lane >> 4;   // k-group 0..3 (k = 8g + j)
  const int base = (int)blockIdx.x * ROWS;

  // N-tile assignment: 19 tiles of 16 -> waves 0..2 get 3, waves 3..7 get 2
  const int t0    = (wv < 3) ? wv * 3 : 9 + (wv - 3) * 2;
  const int ntile = (wv < 3) ? 3 : 2;

  // ---- stage x indices for this block's 16 rows (all 200 steps)
  for (int i = tid; i < SEQ * 16; i += 512)
    x_lds[i >> 4][i & 15] = x[(i >> 4) * BATCHN + base + (i & 15)];
  // ---- zero both h/xe buffers (padding cols must stay zero)
  for (int i = tid; i < ROWS * SROW; i += 512)
    (&s_lds[0][0])[i] = (_Float16)0.f;

  // ---- resident weight fragments (f16) + bias
  half8 whh[KCH][3];
  half8 wih[KCE][3];
  float bias[3];
  #pragma unroll
  for (int tt = 0; tt < 3; tt++) {
    const int n = (t0 + tt) * 16 + r;
    const bool nv = (tt < ntile) && (n < HIDN);
    bias[tt] = nv ? (b_ih[n] + b_hh[n]) : 0.f;
    #pragma unroll
    for (int c = 0; c < KCH; c++)
      whh[c][tt] = loadw(w_hh + (long)n * HIDN, c * 32 + 8 * g, HIDN, nv);
    #pragma unroll
    for (int c = 0; c < KCE; c++)
      wih[c][tt] = loadw(w_ih + (long)n * EMBD, c * 32 + 8 * g, EMBD, nv);
  }

  // xe gather duty: wave6 -> chunks 0..1, wave7 -> chunks 2..3
  const int gc0 = (wv - 6) * 2;

  __syncthreads();

  // ---- pre-stage xe(t=0) into buffer 0
  if (wv >= 6) {
    const int idx = x_lds[0][r];
    const float* erow = emb + (long)idx * EMBD;
    #pragma unroll
    for (int j = 0; j < 2; j++) {
      const int k0 = (gc0 + j) * 32 + 8 * g;
      f32x4 a = (k0 + 3 < EMBD) ? *(const f32x4*)(erow + k0)     : f4z();
      f32x4 b = (k0 + 7 < EMBD) ? *(const f32x4*)(erow + k0 + 4) : f4z();
      *(half8*)&s_lds[r][XE0 + k0] = h8cvt(a, b);
    }
  }
  __syncthreads();

  const _Float16* a_base = &s_lds[r][8 * g];

  // =========================== main scan ===========================
  #pragma unroll 2
  for (int t = 0; t < SEQ; t++) {
    const _Float16* ab = a_base + (t & 1) * BSPAN;    // read buffer
    const int nbuf = ((t + 1) & 1) * BSPAN;           // write buffer (col offset)

    // issue next-step emb gathers early (latency hides under MFMAs)
    f32x4 xg[2][2];
    if (wv >= 6) {
      const int tn = (t + 1 < SEQ) ? t + 1 : t;
      const int idx = x_lds[tn][r];
      const float* erow = emb + (long)idx * EMBD;
      #pragma unroll
      for (int j = 0; j < 2; j++) {
        const int k0 = (gc0 + j) * 32 + 8 * g;
        xg[j][0] = (k0 + 3 < EMBD) ? *(const f32x4*)(erow + k0)     : f4z();
        xg[j][1] = (k0 + 7 < EMBD) ? *(const f32x4*)(erow + k0 + 4) : f4z();
      }
    }

    f32x4 acc[3];
    #pragma unroll
    for (int tt = 0; tt < 3; tt++) {
      f32x4 v = {bias[tt], bias[tt], bias[tt], bias[tt]};
      acc[tt] = v;
    }

    if (ntile == 3) { STEP_BODY(3); } else { STEP_BODY(2); }

    // stage xe(t+1) into the other buffer (no reader conflict; barrier below)
    if (wv >= 6) {
      #pragma unroll
      for (int j = 0; j < 2; j++) {
        const int k0 = (gc0 + j) * 32 + 8 * g;
        *(half8*)&s_lds[r][nbuf + XE0 + k0] = h8cvt(xg[j][0], xg[j][1]);
      }
    }
    // h(t+1) = tanh(pre-act); D: row = 4g+j, col n = tile*16 + r
    #pragma unroll
    for (int tt = 0; tt < 3; tt++) {
      if (tt < ntile) {
        const int n = (t0 + tt) * 16 + r;
        if (n < HIDN) {
          #pragma unroll
          for (int j = 0; j < 4; j++)
            s_lds[4 * g + j][nbuf + n] = (_Float16)tanh_fast(acc[tt][j]);
        }
      }
    }
    __syncthreads();   // single barrier: separates step t reads from step t+1 writes
  }

  // =========================== fc1 (relu) ===========================
  {
    const _Float16* abf = a_base + (SEQ & 1) * BSPAN;  // h(SEQ) buffer
    f32x4 acc1[2];
    const int f0 = wv * 2;   // 16 n-tiles over 8 waves
    #pragma unroll
    for (int ft = 0; ft < 2; ft++) {
      const float bb = fc1b[(f0 + ft) * 16 + r];
      f32x4 v = {bb, bb, bb, bb};
      acc1[ft] = v;
    }
    #pragma unroll
    for (int c = 0; c < KCH; c++) {
      const half8 a = *(const half8*)(abf + c * 32);
      #pragma unroll
      for (int ft = 0; ft < 2; ft++) {
        const int n = (f0 + ft) * 16 + r;
        const half8 b = loadw(fc1w + (long)n * HIDN, c * 32 + 8 * g, HIDN, true);
        acc1[ft] = MFMA32(a, b, acc1[ft]);
      }
    }
    #pragma unroll
    for (int ft = 0; ft < 2; ft++) {
      const int n = (f0 + ft) * 16 + r;
      #pragma unroll
      for (int j = 0; j < 4; j++) {
        const float v = acc1[ft][j];
        h1f[4 * g + j][n] = v > 0.f ? v : 0.f;
      }
    }
  }
  __syncthreads();

  // =========================== fc2 (fp32 scalar) ===========================
  if (wv == 0 && lane < 48) {
    const int m = lane / 3;
    const int n = lane - 3 * m;
    float s = fc2b[n];
    for (int k = 0; k < 256; k++)
      s = __builtin_fmaf(h1f[m][k], fc2w[n * 256 + k], s);
    out[(base + m) * 3 + n] = s;
  }
}

extern "C" void kernel_launch(void* const* d_in, const int* in_sizes, int n_in,
                              void* d_out, int out_size, void* d_ws, size_t ws_size,
                              hipStream_t stream) {
  (void)in_sizes; (void)n_in; (void)d_ws; (void)ws_size; (void)out_size;
  const int*   x   = (const int*)d_in[0];
  const float* emb = (const float*)d_in[1];
  const float* wih = (const float*)d_in[2];
  const float* whh = (const float*)d_in[3];
  const float* bih = (const float*)d_in[4];
  const float* bhh = (const float*)d_in[5];
  const float* f1w = (const float*)d_in[6];
  const float* f1b = (const float*)d_in[7];
  const float* f2w = (const float*)d_in[8];
  const float* f2b = (const float*)d_in[9];
  rnn_fused<<<BATCHN / ROWS, 512, 0, stream>>>(
      x, emb, wih, whh, bih, bhh, f1w, f1b, f2w, f2b, (float*)d_out);
}